// Round 1
// baseline (48000.613 us; speedup 1.0000x reference)
//
#include <hip/hip_runtime.h>
#include <math.h>

// ---------------------------------------------------------------------------
// Refine (RE-GCN style) fp32 baseline.
// N_ENT=20000 N_REL=256 H=512 C=64 K=3 L=2 T=8 E=30000 B=4096
// ---------------------------------------------------------------------------

#define N_ENT 20000
#define N_REL 256
#define HD    512
#define NE    30000
#define NB    4096
#define NT    8

static __device__ __forceinline__ float sigmoidf_(float x) {
  return 1.0f / (1.0f + expf(-x));
}

// ---------------- row L2 normalize: out = x / (||x|| + 1e-8) ---------------
__global__ void rownorm_kernel(const float* __restrict__ in, float* __restrict__ out, int rows) {
  int wid = (blockIdx.x * blockDim.x + threadIdx.x) >> 6;
  int lane = threadIdx.x & 63;
  if (wid >= rows) return;
  const float4* ip = (const float4*)(in + (size_t)wid * HD);
  float4 v0 = ip[lane];
  float4 v1 = ip[lane + 64];
  float s = v0.x * v0.x + v0.y * v0.y + v0.z * v0.z + v0.w * v0.w
          + v1.x * v1.x + v1.y * v1.y + v1.z * v1.z + v1.w * v1.w;
  #pragma unroll
  for (int m = 1; m < 64; m <<= 1) s += __shfl_xor(s, m);
  float inv = 1.0f / (sqrtf(s) + 1e-8f);
  float4* op = (float4*)(out + (size_t)wid * HD);
  v0.x *= inv; v0.y *= inv; v0.z *= inv; v0.w *= inv;
  v1.x *= inv; v1.y *= inv; v1.z *= inv; v1.w *= inv;
  op[lane] = v0; op[lane + 64] = v1;
}

// ---------------- relation aggregation: agg[r] += ent[s], cnt[r]++ ----------
__global__ void agg_rel_kernel(const float* __restrict__ ent, const int* __restrict__ src,
                               const int* __restrict__ erel,
                               float* __restrict__ agg, float* __restrict__ cnt) {
  int wid = (blockIdx.x * blockDim.x + threadIdx.x) >> 6;
  int lane = threadIdx.x & 63;
  if (wid >= NE) return;
  int s = src[wid], r = erel[wid];
  const float* row = ent + (size_t)s * HD;
  float* arow = agg + (size_t)r * HD;
  #pragma unroll
  for (int j = 0; j < 8; ++j) atomicAdd(&arow[lane + 64 * j], row[lane + 64 * j]);
  if (lane == 0) atomicAdd(&cnt[r], 1.0f);
}

// ------------- entity aggregation: agg[d] += h[s] + relh[r], cnt[d]++ -------
__global__ void agg_ent_kernel(const float* __restrict__ h, const float* __restrict__ relh,
                               const int* __restrict__ src, const int* __restrict__ dst,
                               const int* __restrict__ erel,
                               float* __restrict__ agg, float* __restrict__ cnt) {
  int wid = (blockIdx.x * blockDim.x + threadIdx.x) >> 6;
  int lane = threadIdx.x & 63;
  if (wid >= NE) return;
  int s = src[wid], d = dst[wid], r = erel[wid];
  const float* hr = h + (size_t)s * HD;
  const float* rr = relh + (size_t)r * HD;
  float* arow = agg + (size_t)d * HD;
  #pragma unroll
  for (int j = 0; j < 8; ++j) {
    int i = lane + 64 * j;
    atomicAdd(&arow[i], hr[i] + rr[i]);
  }
  if (lane == 0) atomicAdd(&cnt[d], 1.0f);
}

// ---------------- buf[row,:] /= max(cnt[row],1) -----------------------------
__global__ void meandiv_kernel(float* __restrict__ buf, const float* __restrict__ cnt, int rows) {
  int idx = blockIdx.x * blockDim.x + threadIdx.x;  // over rows*128 float4
  if (idx >= rows * (HD / 4)) return;
  int row = idx >> 7;
  float inv = 1.0f / fmaxf(cnt[row], 1.0f);
  float4* p = (float4*)buf + idx;
  float4 v = *p;
  v.x *= inv; v.y *= inv; v.z *= inv; v.w *= inv;
  *p = v;
}

// ---------------- GRU elementwise ------------------------------------------
__global__ void gru_kernel(const float* __restrict__ gi, const float* __restrict__ gh,
                           float* __restrict__ relh) {
  int i = blockIdx.x * blockDim.x + threadIdx.x;  // over 256*512
  if (i >= N_REL * HD) return;
  int row = i >> 9, col = i & 511;
  const float* gir = gi + (size_t)row * 1536;
  const float* ghr = gh + (size_t)row * 1536;
  float ir = gir[col], iz = gir[col + 512], inn = gir[col + 1024];
  float hr = ghr[col], hz = ghr[col + 512], hn = ghr[col + 1024];
  float r = sigmoidf_(ir + hr);
  float z = sigmoidf_(iz + hz);
  float n = tanhf(inn + r * hn);
  relh[i] = (1.0f - z) * n + z * relh[i];
}

// ---------------- gather rows ----------------------------------------------
__global__ void gather_kernel(const float* __restrict__ table, const int* __restrict__ idx,
                              float* __restrict__ out, int rows) {
  int i = blockIdx.x * blockDim.x + threadIdx.x;  // over rows*128 float4
  if (i >= rows * (HD / 4)) return;
  int row = i >> 7, q = i & 127;
  ((float4*)out)[i] = ((const float4*)(table + (size_t)idx[row] * HD))[q];
}

// ---------------- bias + relu in place (4096x512) --------------------------
__global__ void biasrelu_kernel(float* __restrict__ buf, const float* __restrict__ bias) {
  int i = blockIdx.x * blockDim.x + threadIdx.x;
  if (i >= NB * HD) return;
  int col = i & 511;
  buf[i] = fmaxf(buf[i] + bias[col], 0.0f);
}

// ---------------------------------------------------------------------------
// Generic fp32 GEMM: C(M,N) = act(A(M,K) @ B [+ bias] [+ D])
// TRANSB=0: B (K,N) row-major.  TRANSB=1: B (N,K) row-major.
// ACT: 0 none, 1 relu, 3 gate-blend (u=sigmoid(acc+bias); C = u*D + (1-u)*C).
// BM=BN=128, BK=16, 256 threads, 8x8 microtile (rows/cols split 64-apart).
// ---------------------------------------------------------------------------
template <int TRANSB, int ADDC, int BIAS, int ACT>
__global__ __launch_bounds__(256)
void gemm128_kernel(const float* __restrict__ A, const float* __restrict__ B,
                    const float* __restrict__ bias, const float* __restrict__ D,
                    float* __restrict__ C, int M, int N, int K) {
  __shared__ float As[16][132];   // padded: +4 keeps b128 alignment, kills bank conflicts
  __shared__ float Bs[16][128];
  const int tid = threadIdx.x;
  const int tx = tid & 15, ty = tid >> 4;
  const int m0 = blockIdx.x * 128, n0 = blockIdx.y * 128;
  float acc[8][8] = {};

  for (int k0 = 0; k0 < K; k0 += 16) {
    __syncthreads();
    #pragma unroll
    for (int i = 0; i < 2; ++i) {
      int idx = tid + 256 * i;
      int row = idx >> 2, kq = (idx & 3) << 2;
      float4 av = make_float4(0.f, 0.f, 0.f, 0.f);
      if (m0 + row < M) av = *(const float4*)(A + (size_t)(m0 + row) * K + k0 + kq);
      As[kq + 0][row] = av.x; As[kq + 1][row] = av.y;
      As[kq + 2][row] = av.z; As[kq + 3][row] = av.w;
    }
    if (TRANSB == 0) {
      #pragma unroll
      for (int i = 0; i < 2; ++i) {
        int idx = tid + 256 * i;
        int k = idx >> 5, nq = (idx & 31) << 2;
        float4 bv = make_float4(0.f, 0.f, 0.f, 0.f);
        if (n0 + nq < N) bv = *(const float4*)(B + (size_t)(k0 + k) * N + n0 + nq);
        *(float4*)&Bs[k][nq] = bv;
      }
    } else {
      #pragma unroll
      for (int i = 0; i < 2; ++i) {
        int idx = tid + 256 * i;
        int n = idx >> 2, kq = (idx & 3) << 2;
        float4 bv = make_float4(0.f, 0.f, 0.f, 0.f);
        if (n0 + n < N) bv = *(const float4*)(B + (size_t)(n0 + n) * K + k0 + kq);
        Bs[kq + 0][n] = bv.x; Bs[kq + 1][n] = bv.y;
        Bs[kq + 2][n] = bv.z; Bs[kq + 3][n] = bv.w;
      }
    }
    __syncthreads();
    #pragma unroll
    for (int kk = 0; kk < 16; ++kk) {
      float a[8], b[8];
      *(float4*)&a[0] = *(const float4*)&As[kk][ty * 4];
      *(float4*)&a[4] = *(const float4*)&As[kk][64 + ty * 4];
      *(float4*)&b[0] = *(const float4*)&Bs[kk][tx * 4];
      *(float4*)&b[4] = *(const float4*)&Bs[kk][64 + tx * 4];
      #pragma unroll
      for (int i = 0; i < 8; ++i)
        #pragma unroll
        for (int j = 0; j < 8; ++j)
          acc[i][j] = fmaf(a[i], b[j], acc[i][j]);
    }
  }

  #pragma unroll
  for (int rh = 0; rh < 2; ++rh)
    #pragma unroll
    for (int i = 0; i < 4; ++i) {
      int m = m0 + rh * 64 + ty * 4 + i;
      if (m >= M) continue;
      size_t ro = (size_t)m * N;
      #pragma unroll
      for (int ch = 0; ch < 2; ++ch) {
        int n = n0 + ch * 64 + tx * 4;
        if (n >= N) continue;
        float v[4];
        #pragma unroll
        for (int j = 0; j < 4; ++j) v[j] = acc[rh * 4 + i][ch * 4 + j];
        if (BIAS) {
          #pragma unroll
          for (int j = 0; j < 4; ++j) v[j] += bias[n + j];
        }
        if (ADDC) {
          float4 d4 = *(const float4*)&D[ro + n];
          v[0] += d4.x; v[1] += d4.y; v[2] += d4.z; v[3] += d4.w;
        }
        if (ACT == 1) {
          #pragma unroll
          for (int j = 0; j < 4; ++j) v[j] = fmaxf(v[j], 0.0f);
        }
        if (ACT == 3) {
          float4 h4 = *(const float4*)&D[ro + n];
          float4 e4 = *(const float4*)&C[ro + n];
          float hh[4] = {h4.x, h4.y, h4.z, h4.w};
          float ee[4] = {e4.x, e4.y, e4.z, e4.w};
          #pragma unroll
          for (int j = 0; j < 4; ++j) {
            float u = sigmoidf_(v[j]);
            v[j] = u * hh[j] + (1.0f - u) * ee[j];
          }
        }
        float4 o4 = make_float4(v[0], v[1], v[2], v[3]);
        *(float4*)&C[ro + n] = o4;
      }
    }
}

// ---------------------------------------------------------------------------
// Fused conv1d('SAME',K=3) + relu + flatten + FC GEMM (no bias/act here —
// partial sums accumulated by f32 atomics; bias+relu applied by biasrelu).
// A_conv[b, c*512+h] = relu( sum_ci sum_t X[ci][b, h+t-1] * w[c,ci,t] + cb[c] )
// out += A_conv(4096,32768) @ fw(32768,512)   split-K over c-halves (blockIdx.z).
// ---------------------------------------------------------------------------
template <int CIN>
__global__ __launch_bounds__(256)
void convfc_kernel(const float* __restrict__ X0a, const float* __restrict__ X1a,
                   const float* __restrict__ X2a, const float* __restrict__ cwA,
                   const float* __restrict__ cbA, const float* __restrict__ fwA,
                   const float* __restrict__ X0b, const float* __restrict__ X1b,
                   const float* __restrict__ X2b, const float* __restrict__ cwB,
                   const float* __restrict__ cbB, const float* __restrict__ fwB,
                   float* __restrict__ outA, float* __restrict__ outB) {
  __shared__ float As[16][132];
  __shared__ float Bs[16][128];
  const int pair = blockIdx.z >> 1;
  const int ks = blockIdx.z & 1;
  const float* X[3];
  const float* cw; const float* cb; const float* fw; float* outp;
  if (pair == 0) { X[0] = X0a; X[1] = X1a; X[2] = X2a; cw = cwA; cb = cbA; fw = fwA; outp = outA; }
  else           { X[0] = X0b; X[1] = X1b; X[2] = X2b; cw = cwB; cb = cbB; fw = fwB; outp = outB; }

  const int tid = threadIdx.x;
  const int tx = tid & 15, ty = tid >> 4;
  const int m0 = blockIdx.x * 128, n0 = blockIdx.y * 128;
  float acc[8][8] = {};

  for (int c = ks * 32; c < ks * 32 + 32; ++c) {
    float w[CIN][3];
    #pragma unroll
    for (int ci = 0; ci < CIN; ++ci)
      #pragma unroll
      for (int t = 0; t < 3; ++t) w[ci][t] = cw[(c * CIN + ci) * 3 + t];
    float cbv = cb[c];

    for (int h0 = 0; h0 < HD; h0 += 16) {
      __syncthreads();
      // compute conv A-tile (128 b-rows x 16 k) on the fly
      #pragma unroll
      for (int i = 0; i < 8; ++i) {
        int idx = tid + 256 * i;
        int m = idx >> 4, kk = idx & 15;
        int h = h0 + kk;
        float v = cbv;
        #pragma unroll
        for (int ci = 0; ci < CIN; ++ci) {
          const float* xr = X[ci] + (size_t)(m0 + m) * HD + h;
          if (h > 0) v = fmaf(xr[-1], w[ci][0], v);
          v = fmaf(xr[0], w[ci][1], v);
          if (h < HD - 1) v = fmaf(xr[1], w[ci][2], v);
        }
        As[kk][m] = fmaxf(v, 0.0f);
      }
      // load fcW tile
      int k0 = c * HD + h0;
      #pragma unroll
      for (int i = 0; i < 2; ++i) {
        int idx = tid + 256 * i;
        int k = idx >> 5, nq = (idx & 31) << 2;
        *(float4*)&Bs[k][nq] = *(const float4*)&fw[(size_t)(k0 + k) * HD + n0 + nq];
      }
      __syncthreads();
      #pragma unroll
      for (int kk = 0; kk < 16; ++kk) {
        float a[8], b[8];
        *(float4*)&a[0] = *(const float4*)&As[kk][ty * 4];
        *(float4*)&a[4] = *(const float4*)&As[kk][64 + ty * 4];
        *(float4*)&b[0] = *(const float4*)&Bs[kk][tx * 4];
        *(float4*)&b[4] = *(const float4*)&Bs[kk][64 + tx * 4];
        #pragma unroll
        for (int i = 0; i < 8; ++i)
          #pragma unroll
          for (int j = 0; j < 8; ++j)
            acc[i][j] = fmaf(a[i], b[j], acc[i][j]);
      }
    }
  }

  #pragma unroll
  for (int rh = 0; rh < 2; ++rh)
    #pragma unroll
    for (int i = 0; i < 4; ++i) {
      int m = m0 + rh * 64 + ty * 4 + i;
      size_t ro = (size_t)m * HD;
      #pragma unroll
      for (int ch = 0; ch < 2; ++ch) {
        int n = n0 + ch * 64 + tx * 4;
        #pragma unroll
        for (int j = 0; j < 4; ++j)
          atomicAdd(&outp[ro + n + j], acc[rh * 4 + i][ch * 4 + j]);
      }
    }
}

// ---------------------------------------------------------------------------
extern "C" void kernel_launch(void* const* d_in, const int* in_sizes, int n_in,
                              void* d_out, int out_size, void* d_ws, size_t ws_size,
                              hipStream_t stream) {
  const float* ent_embeds = (const float*)d_in[0];
  const float* rel_embeds = (const float*)d_in[1];
  const float* W_msg  = (const float*)d_in[2];
  const float* W_self = (const float*)d_in[3];
  const float* gru_Wih = (const float*)d_in[4];
  const float* gru_Whh = (const float*)d_in[5];
  const float* gru_bih = (const float*)d_in[6];
  const float* gru_bhh = (const float*)d_in[7];
  const float* gate_W = (const float*)d_in[8];
  const float* gate_b = (const float*)d_in[9];
  const float* e_conv1 = (const float*)d_in[10]; const float* e_cb1 = (const float*)d_in[11];
  const float* e_fc1   = (const float*)d_in[12]; const float* e_fb1 = (const float*)d_in[13];
  const float* e_conv2 = (const float*)d_in[14]; const float* e_cb2 = (const float*)d_in[15];
  const float* e_fc2   = (const float*)d_in[16]; const float* e_fb2 = (const float*)d_in[17];
  const float* r_conv1 = (const float*)d_in[18]; const float* r_cb1 = (const float*)d_in[19];
  const float* r_fc1   = (const float*)d_in[20]; const float* r_fb1 = (const float*)d_in[21];
  const float* r_conv2 = (const float*)d_in[22]; const float* r_cb2 = (const float*)d_in[23];
  const float* r_fc2   = (const float*)d_in[24]; const float* r_fb2 = (const float*)d_in[25];
  const int* src  = (const int*)d_in[26];
  const int* dst  = (const int*)d_in[27];
  const int* erel = (const int*)d_in[28];
  const int* subj = (const int*)d_in[29];
  const int* rel  = (const int*)d_in[30];
  const int* obj  = (const int*)d_in[31];
  float* out = (float*)d_out;

  // -------- workspace layout (floats); keep memset groups contiguous --------
  float* w = (float*)d_ws;
  float* ent   = w; w += (size_t)N_ENT * HD;       // 10,240,000
  float* relh  = w; w += (size_t)N_REL * HD;       // 131,072
  float* aggR  = w; w += (size_t)N_REL * HD;       // 131,072   (zeroed with cntR)
  float* cntR  = w; w += N_REL;                    // 256
  float* precomp = w; w += (size_t)N_REL * 1536;   // 393,216
  float* gi    = w; w += (size_t)N_REL * 1536;
  float* gh    = w; w += (size_t)N_REL * 1536;
  float* aggE  = w; w += (size_t)N_ENT * HD;       // zeroed with cntE
  float* cntE  = w; w += N_ENT;
  float* tmp   = w; w += (size_t)N_ENT * HD;
  float* h0b   = w; w += (size_t)N_ENT * HD;
  float* h1b   = w; w += (size_t)N_ENT * HD;
  float* se    = w; w += (size_t)NB * HD;
  float* re_   = w; w += (size_t)NB * HD;
  float* oe    = w; w += (size_t)NB * HD;
  float* o1    = w; w += (size_t)NB * HD;          // o1,q1 contiguous (one memset)
  float* q1    = w; w += (size_t)NB * HD;
  float* o2    = w; w += (size_t)NB * HD;          // o2,q2 contiguous
  float* q2    = w; w += (size_t)NB * HD;

  const dim3 g_gru(2, 12);     // 256 x 1536
  const dim3 g_ent(157, 4);    // 20000 x 512

  // -------- init --------
  rownorm_kernel<<<N_ENT / 4, 256, 0, stream>>>(ent_embeds, ent, N_ENT);
  hipMemcpyAsync(relh, rel_embeds, (size_t)N_REL * HD * 4, hipMemcpyDeviceToDevice, stream);
  // precomp = rel_embeds @ Wih[512:] + bih   (constant across timesteps)
  gemm128_kernel<0, 0, 1, 0><<<g_gru, 256, 0, stream>>>(
      rel_embeds, gru_Wih + (size_t)512 * 1536, gru_bih, nullptr, precomp, N_REL, 1536, HD);

  // -------- timestep loop --------
  for (int t = 0; t < NT; ++t) {
    const int* st = src + t * NE;
    const int* dt = dst + t * NE;
    const int* rt = erel + t * NE;

    // relation evolution
    hipMemsetAsync(aggR, 0, ((size_t)N_REL * HD + N_REL) * 4, stream);
    agg_rel_kernel<<<NE / 4, 256, 0, stream>>>(ent, st, rt, aggR, cntR);
    meandiv_kernel<<<(N_REL * HD / 4) / 256, 256, 0, stream>>>(aggR, cntR, N_REL);
    gemm128_kernel<0, 1, 0, 0><<<g_gru, 256, 0, stream>>>(
        aggR, gru_Wih, nullptr, precomp, gi, N_REL, 1536, HD);
    gemm128_kernel<0, 0, 1, 0><<<g_gru, 256, 0, stream>>>(
        relh, gru_Whh, gru_bhh, nullptr, gh, N_REL, 1536, HD);
    gru_kernel<<<(N_REL * HD) / 256, 256, 0, stream>>>(gi, gh, relh);

    // entity evolution: aggregate-then-transform (linear, exact)
    const float* hcur = ent;
    float* bufs[2] = {h0b, h1b};
    for (int l = 0; l < 2; ++l) {
      hipMemsetAsync(aggE, 0, ((size_t)N_ENT * HD + N_ENT) * 4, stream);
      agg_ent_kernel<<<NE / 4, 256, 0, stream>>>(hcur, relh, st, dt, rt, aggE, cntE);
      meandiv_kernel<<<(N_ENT * HD / 4 + 255) / 256, 256, 0, stream>>>(aggE, cntE, N_ENT);
      gemm128_kernel<0, 0, 0, 0><<<g_ent, 256, 0, stream>>>(
          aggE, W_msg + (size_t)l * HD * HD, nullptr, nullptr, tmp, N_ENT, HD, HD);
      gemm128_kernel<0, 1, 0, 1><<<g_ent, 256, 0, stream>>>(
          hcur, W_self + (size_t)l * HD * HD, nullptr, tmp, bufs[l], N_ENT, HD, HD);
      hcur = bufs[l];
    }
    rownorm_kernel<<<N_ENT / 4, 256, 0, stream>>>(h1b, h1b, N_ENT);
    // time gate fused into GEMM epilogue: ent = u*h + (1-u)*ent, u=sigmoid(h@gateW+b)
    gemm128_kernel<0, 0, 1, 3><<<g_ent, 256, 0, stream>>>(
        h1b, gate_W, gate_b, h1b, ent, N_ENT, HD, HD);
  }

  // -------- decoder --------
  gather_kernel<<<(NB * HD / 4) / 256, 256, 0, stream>>>(ent, subj, se, NB);
  gather_kernel<<<(NB * HD / 4) / 256, 256, 0, stream>>>(relh, rel, re_, NB);
  gather_kernel<<<(NB * HD / 4) / 256, 256, 0, stream>>>(ent, obj, oe, NB);

  const dim3 gcf(32, 4, 4);  // (M/128, N/128, pair*2 + ksplit)
  hipMemsetAsync(o1, 0, (size_t)2 * NB * HD * 4, stream);
  convfc_kernel<2><<<gcf, 256, 0, stream>>>(
      se, re_, nullptr, e_conv1, e_cb1, e_fc1,
      se, oe, nullptr, r_conv1, r_cb1, r_fc1, o1, q1);
  biasrelu_kernel<<<(NB * HD) / 256, 256, 0, stream>>>(o1, e_fb1);
  biasrelu_kernel<<<(NB * HD) / 256, 256, 0, stream>>>(q1, r_fb1);

  hipMemsetAsync(o2, 0, (size_t)2 * NB * HD * 4, stream);
  convfc_kernel<3><<<gcf, 256, 0, stream>>>(
      o1, se, re_, e_conv2, e_cb2, e_fc2,
      q1, se, oe, r_conv2, r_cb2, r_fc2, o2, q2);
  biasrelu_kernel<<<(NB * HD) / 256, 256, 0, stream>>>(o2, e_fb2);
  biasrelu_kernel<<<(NB * HD) / 256, 256, 0, stream>>>(q2, r_fb2);

  // -------- logits (NT layout: both operands row-major, contract last dim) --
  const dim3 gl_big(32, 157);  // 4096 x 20000
  const dim3 gl_sm(32, 2);     // 4096 x 256
  size_t off0 = 0;
  size_t off1 = (size_t)NB * N_ENT;                    // 81,920,000
  size_t off2 = off1 + (size_t)NB * N_REL;             // 82,968,576
  size_t off3 = off2 + (size_t)NB * N_ENT;             // 164,888,576
  gemm128_kernel<1, 0, 0, 0><<<gl_big, 256, 0, stream>>>(
      o1, ent, nullptr, nullptr, out + off0, NB, N_ENT, HD);
  gemm128_kernel<1, 0, 0, 0><<<gl_sm, 256, 0, stream>>>(
      q1, relh, nullptr, nullptr, out + off1, NB, N_REL, HD);
  gemm128_kernel<1, 0, 0, 0><<<gl_big, 256, 0, stream>>>(
      o2, ent, nullptr, nullptr, out + off2, NB, N_ENT, HD);
  gemm128_kernel<1, 0, 0, 0><<<gl_sm, 256, 0, stream>>>(
      q2, relh, nullptr, nullptr, out + off3, NB, N_REL, HD);
}

// Round 2
// 12935.330 us; speedup vs baseline: 3.7108x; 3.7108x over previous
//
#include <hip/hip_runtime.h>
#include <math.h>

// ---------------------------------------------------------------------------
// Refine (RE-GCN style): fp32 recurrence + bf16-MFMA decoder.
// N_ENT=20000 N_REL=256 H=512 C=64 K=3 L=2 T=8 E=30000 B=4096
// ---------------------------------------------------------------------------

#define N_ENT 20000
#define N_REL 256
#define HD    512
#define NE    30000
#define NB    4096
#define NT    8

typedef __attribute__((ext_vector_type(8))) short          bf16x8;
typedef __attribute__((ext_vector_type(4))) float          f32x4;
typedef __attribute__((ext_vector_type(8))) unsigned short u16x8;
typedef __attribute__((ext_vector_type(4))) unsigned short u16x4;

static __device__ __forceinline__ float sigmoidf_(float x) {
  return 1.0f / (1.0f + expf(-x));
}
static __device__ __forceinline__ unsigned short f2bf(float f) {  // RNE
  unsigned u = __float_as_uint(f);
  return (unsigned short)((u + 0x7FFFu + ((u >> 16) & 1u)) >> 16);
}
static __device__ __forceinline__ float bf2f(unsigned short s) {
  return __uint_as_float(((unsigned)s) << 16);
}

// ---------------- row L2 normalize: out = x / (||x|| + 1e-8) ---------------
__global__ void rownorm_kernel(const float* __restrict__ in, float* __restrict__ out, int rows) {
  int wid = (blockIdx.x * blockDim.x + threadIdx.x) >> 6;
  int lane = threadIdx.x & 63;
  if (wid >= rows) return;
  const float4* ip = (const float4*)(in + (size_t)wid * HD);
  float4 v0 = ip[lane];
  float4 v1 = ip[lane + 64];
  float s = v0.x * v0.x + v0.y * v0.y + v0.z * v0.z + v0.w * v0.w
          + v1.x * v1.x + v1.y * v1.y + v1.z * v1.z + v1.w * v1.w;
  #pragma unroll
  for (int m = 1; m < 64; m <<= 1) s += __shfl_xor(s, m);
  float inv = 1.0f / (sqrtf(s) + 1e-8f);
  float4* op = (float4*)(out + (size_t)wid * HD);
  v0.x *= inv; v0.y *= inv; v0.z *= inv; v0.w *= inv;
  v1.x *= inv; v1.y *= inv; v1.z *= inv; v1.w *= inv;
  op[lane] = v0; op[lane + 64] = v1;
}

// ---------------- relation aggregation: agg[r] += ent[s], cnt[r]++ ----------
__global__ void agg_rel_kernel(const float* __restrict__ ent, const int* __restrict__ src,
                               const int* __restrict__ erel,
                               float* __restrict__ agg, float* __restrict__ cnt) {
  int wid = (blockIdx.x * blockDim.x + threadIdx.x) >> 6;
  int lane = threadIdx.x & 63;
  if (wid >= NE) return;
  int s = src[wid], r = erel[wid];
  const float* row = ent + (size_t)s * HD;
  float* arow = agg + (size_t)r * HD;
  #pragma unroll
  for (int j = 0; j < 8; ++j) atomicAdd(&arow[lane + 64 * j], row[lane + 64 * j]);
  if (lane == 0) atomicAdd(&cnt[r], 1.0f);
}

// ------------- entity aggregation: agg[d] += h[s] + relh[r], cnt[d]++ -------
__global__ void agg_ent_kernel(const float* __restrict__ h, const float* __restrict__ relh,
                               const int* __restrict__ src, const int* __restrict__ dst,
                               const int* __restrict__ erel,
                               float* __restrict__ agg, float* __restrict__ cnt) {
  int wid = (blockIdx.x * blockDim.x + threadIdx.x) >> 6;
  int lane = threadIdx.x & 63;
  if (wid >= NE) return;
  int s = src[wid], d = dst[wid], r = erel[wid];
  const float* hr = h + (size_t)s * HD;
  const float* rr = relh + (size_t)r * HD;
  float* arow = agg + (size_t)d * HD;
  #pragma unroll
  for (int j = 0; j < 8; ++j) {
    int i = lane + 64 * j;
    atomicAdd(&arow[i], hr[i] + rr[i]);
  }
  if (lane == 0) atomicAdd(&cnt[d], 1.0f);
}

// ---------------- buf[row,:] /= max(cnt[row],1) -----------------------------
__global__ void meandiv_kernel(float* __restrict__ buf, const float* __restrict__ cnt, int rows) {
  int idx = blockIdx.x * blockDim.x + threadIdx.x;
  if (idx >= rows * (HD / 4)) return;
  int row = idx >> 7;
  float inv = 1.0f / fmaxf(cnt[row], 1.0f);
  float4* p = (float4*)buf + idx;
  float4 v = *p;
  v.x *= inv; v.y *= inv; v.z *= inv; v.w *= inv;
  *p = v;
}

// ---------------- GRU elementwise ------------------------------------------
__global__ void gru_kernel(const float* __restrict__ gi, const float* __restrict__ gh,
                           float* __restrict__ relh) {
  int i = blockIdx.x * blockDim.x + threadIdx.x;
  if (i >= N_REL * HD) return;
  int row = i >> 9, col = i & 511;
  const float* gir = gi + (size_t)row * 1536;
  const float* ghr = gh + (size_t)row * 1536;
  float ir = gir[col], iz = gir[col + 512], inn = gir[col + 1024];
  float hr = ghr[col], hz = ghr[col + 512], hn = ghr[col + 1024];
  float r = sigmoidf_(ir + hr);
  float z = sigmoidf_(iz + hz);
  float n = tanhf(inn + r * hn);
  relh[i] = (1.0f - z) * n + z * relh[i];
}

// ---------------- gather rows (f32) ----------------------------------------
__global__ void gather_kernel(const float* __restrict__ table, const int* __restrict__ idx,
                              float* __restrict__ out, int rows) {
  int i = blockIdx.x * blockDim.x + threadIdx.x;
  if (i >= rows * (HD / 4)) return;
  int row = i >> 7, q = i & 127;
  ((float4*)out)[i] = ((const float4*)(table + (size_t)idx[row] * HD))[q];
}

// ---------------- flat f32 -> bf16 convert (n multiple of 8) ---------------
__global__ void f2b_kernel(const float* __restrict__ in, unsigned short* __restrict__ out, int n) {
  int i = blockIdx.x * blockDim.x + threadIdx.x;
  if (i * 8 >= n) return;
  float4 a = *(const float4*)&in[i * 8];
  float4 b = *(const float4*)&in[i * 8 + 4];
  u16x8 pk = {f2bf(a.x), f2bf(a.y), f2bf(a.z), f2bf(a.w),
              f2bf(b.x), f2bf(b.y), f2bf(b.z), f2bf(b.w)};
  *(u16x8*)&out[i * 8] = pk;
}

// ---------------------------------------------------------------------------
// Generic fp32 GEMM (recurrence only): C = act(A@B [+bias] [+D])
// ---------------------------------------------------------------------------
template <int TRANSB, int ADDC, int BIAS, int ACT>
__global__ __launch_bounds__(256)
void gemm128_kernel(const float* __restrict__ A, const float* __restrict__ B,
                    const float* __restrict__ bias, const float* __restrict__ D,
                    float* __restrict__ C, int M, int N, int K) {
  __shared__ float As[16][132];
  __shared__ float Bs[16][128];
  const int tid = threadIdx.x;
  const int tx = tid & 15, ty = tid >> 4;
  const int m0 = blockIdx.x * 128, n0 = blockIdx.y * 128;
  float acc[8][8] = {};

  for (int k0 = 0; k0 < K; k0 += 16) {
    __syncthreads();
    #pragma unroll
    for (int i = 0; i < 2; ++i) {
      int idx = tid + 256 * i;
      int row = idx >> 2, kq = (idx & 3) << 2;
      float4 av = make_float4(0.f, 0.f, 0.f, 0.f);
      if (m0 + row < M) av = *(const float4*)(A + (size_t)(m0 + row) * K + k0 + kq);
      As[kq + 0][row] = av.x; As[kq + 1][row] = av.y;
      As[kq + 2][row] = av.z; As[kq + 3][row] = av.w;
    }
    if (TRANSB == 0) {
      #pragma unroll
      for (int i = 0; i < 2; ++i) {
        int idx = tid + 256 * i;
        int k = idx >> 5, nq = (idx & 31) << 2;
        float4 bv = make_float4(0.f, 0.f, 0.f, 0.f);
        if (n0 + nq < N) bv = *(const float4*)(B + (size_t)(k0 + k) * N + n0 + nq);
        *(float4*)&Bs[k][nq] = bv;
      }
    } else {
      #pragma unroll
      for (int i = 0; i < 2; ++i) {
        int idx = tid + 256 * i;
        int n = idx >> 2, kq = (idx & 3) << 2;
        float4 bv = make_float4(0.f, 0.f, 0.f, 0.f);
        if (n0 + n < N) bv = *(const float4*)(B + (size_t)(n0 + n) * K + k0 + kq);
        Bs[kq + 0][n] = bv.x; Bs[kq + 1][n] = bv.y;
        Bs[kq + 2][n] = bv.z; Bs[kq + 3][n] = bv.w;
      }
    }
    __syncthreads();
    #pragma unroll
    for (int kk = 0; kk < 16; ++kk) {
      float a[8], b[8];
      *(float4*)&a[0] = *(const float4*)&As[kk][ty * 4];
      *(float4*)&a[4] = *(const float4*)&As[kk][64 + ty * 4];
      *(float4*)&b[0] = *(const float4*)&Bs[kk][tx * 4];
      *(float4*)&b[4] = *(const float4*)&Bs[kk][64 + tx * 4];
      #pragma unroll
      for (int i = 0; i < 8; ++i)
        #pragma unroll
        for (int j = 0; j < 8; ++j)
          acc[i][j] = fmaf(a[i], b[j], acc[i][j]);
    }
  }

  #pragma unroll
  for (int rh = 0; rh < 2; ++rh)
    #pragma unroll
    for (int i = 0; i < 4; ++i) {
      int m = m0 + rh * 64 + ty * 4 + i;
      if (m >= M) continue;
      size_t ro = (size_t)m * N;
      #pragma unroll
      for (int ch = 0; ch < 2; ++ch) {
        int n = n0 + ch * 64 + tx * 4;
        if (n >= N) continue;
        float v[4];
        #pragma unroll
        for (int j = 0; j < 4; ++j) v[j] = acc[rh * 4 + i][ch * 4 + j];
        if (BIAS) {
          #pragma unroll
          for (int j = 0; j < 4; ++j) v[j] += bias[n + j];
        }
        if (ADDC) {
          float4 d4 = *(const float4*)&D[ro + n];
          v[0] += d4.x; v[1] += d4.y; v[2] += d4.z; v[3] += d4.w;
        }
        if (ACT == 1) {
          #pragma unroll
          for (int j = 0; j < 4; ++j) v[j] = fmaxf(v[j], 0.0f);
        }
        if (ACT == 3) {
          float4 h4 = *(const float4*)&D[ro + n];
          float4 e4 = *(const float4*)&C[ro + n];
          float hh[4] = {h4.x, h4.y, h4.z, h4.w};
          float ee[4] = {e4.x, e4.y, e4.z, e4.w};
          #pragma unroll
          for (int j = 0; j < 4; ++j) {
            float u = sigmoidf_(v[j]);
            v[j] = u * hh[j] + (1.0f - u) * ee[j];
          }
        }
        float4 o4 = make_float4(v[0], v[1], v[2], v[3]);
        *(float4*)&C[ro + n] = o4;
      }
    }
}

// ---------------------------------------------------------------------------
// pack_fw: fw (32768x512 f32, k-major) -> bf16 LDS-image layout:
// step s (32 k): ushort idx = s*16384 + n*32 + ((g ^ ((n>>2)&3))<<3) + j
// holding fw[s*32 + g*8 + j][n].  (g = kgroup 0..3, j = 0..7)
// ---------------------------------------------------------------------------
__global__ __launch_bounds__(256)
void pack_fw_kernel(const float* __restrict__ f0, const float* __restrict__ f1,
                    const float* __restrict__ f2, const float* __restrict__ f3,
                    unsigned short* __restrict__ o0, unsigned short* __restrict__ o1,
                    unsigned short* __restrict__ o2, unsigned short* __restrict__ o3) {
  __shared__ float L[32][512];
  const float* fw; unsigned short* op;
  switch (blockIdx.y) {
    case 0: fw = f0; op = o0; break;
    case 1: fw = f1; op = o1; break;
    case 2: fw = f2; op = o2; break;
    default: fw = f3; op = o3; break;
  }
  int s = blockIdx.x, tid = threadIdx.x;
  #pragma unroll
  for (int i = 0; i < 16; ++i) {
    int idx = tid + 256 * i;                 // 32*128 float4
    int r = idx >> 7, cq = (idx & 127) << 2;
    *(float4*)&L[r][cq] = *(const float4*)&fw[(size_t)(s * 32 + r) * 512 + cq];
  }
  __syncthreads();
  #pragma unroll
  for (int ii = 0; ii < 8; ++ii) {
    int slot = tid + 256 * ii;               // 2048 slots
    int n = slot >> 2, g = slot & 3;
    u16x8 pk;
    #pragma unroll
    for (int j = 0; j < 8; ++j) pk[j] = f2bf(L[g * 8 + j][n]);
    size_t off = (size_t)s * 16384 + n * 32 + ((g ^ ((n >> 2) & 3)) << 3);
    *(u16x8*)&op[off] = pk;
  }
}

// ---------------------------------------------------------------------------
// Fused conv1d('SAME',K=3)+relu -> bf16 MFMA GEMM against packed fw.
// BM=128, BN=256, BK=32. Grid (32 mtiles, 2 nhalves, path*4 + ksplit).
// Each block owns 16 channels (KSPLIT=4); writes its f32 partial buffer.
// ---------------------------------------------------------------------------
template <int CIN>
__global__ __launch_bounds__(256, 2)
void convfc_mfma(const float* __restrict__ X0e, const float* __restrict__ X1e,
                 const float* __restrict__ X2e, const float* __restrict__ cwE,
                 const float* __restrict__ cbE, const unsigned short* __restrict__ fwpE,
                 const float* __restrict__ X0r, const float* __restrict__ X1r,
                 const float* __restrict__ X2r, const float* __restrict__ cwR,
                 const float* __restrict__ cbR, const unsigned short* __restrict__ fwpR,
                 float* __restrict__ partE, float* __restrict__ partR) {
  __shared__ unsigned short As[128 * 32];   // 8KB  : m*32 + slot*8 ; slot = g ^ ((m>>2)&3)
  __shared__ unsigned short Bs[256 * 32];   // 16KB : nl*32 + slot*8

  const int tid = threadIdx.x;
  const int lane = tid & 63;
  const int w = tid >> 6;
  const int wm = w >> 1, wn = w & 1;        // 2x2 waves, wave tile 64m x 128n
  const int m0 = blockIdx.x * 128;
  const int n0 = blockIdx.y * 256;
  const int ks = blockIdx.z & 3;
  const int path = blockIdx.z >> 2;

  const float* X[CIN];
  const float* cw; const float* cb; const unsigned short* fwp; float* part;
  if (path == 0) {
    X[0] = X0e; X[1] = X1e; if constexpr (CIN == 3) X[2] = X2e;
    cw = cwE; cb = cbE; fwp = fwpE; part = partE;
  } else {
    X[0] = X0r; X[1] = X1r; if constexpr (CIN == 3) X[2] = X2r;
    cw = cwR; cb = cbR; fwp = fwpR; part = partR;
  }
  part += (size_t)ks * (NB * HD);

  f32x4 acc[4][8];
  #pragma unroll
  for (int i = 0; i < 4; ++i)
    #pragma unroll
    for (int j = 0; j < 8; ++j) acc[i][j] = (f32x4){0.f, 0.f, 0.f, 0.f};

  float wv[CIN][3];
  float cbv = 0.f;
  const int lr = lane & 15, lg = lane >> 4;

  for (int sl = 0; sl < 256; ++sl) {
    int c = ks * 16 + (sl >> 4);
    int hb = (sl & 15) * 32;
    if ((sl & 15) == 0) {
      #pragma unroll
      for (int ci = 0; ci < CIN; ++ci)
        #pragma unroll
        for (int t = 0; t < 3; ++t) wv[ci][t] = cw[(c * CIN + ci) * 3 + t];
      cbv = cb[c];
    }
    __syncthreads();   // protect LDS from previous iteration's readers

    // ---- stage B: copy 16KB pre-swizzled image slice (identity copy) ----
    {
      const unsigned short* src = fwp + (size_t)(c * 16 + (sl & 15)) * 16384 + n0 * 32;
      #pragma unroll
      for (int q = 0; q < 4; ++q) {
        int off = q * 2048 + tid * 8;
        *(u16x8*)&Bs[off] = *(const u16x8*)&src[off];
      }
    }
    // ---- conv A: 2 chunks of 8 h-values each ----
    #pragma unroll
    for (int cc = 0; cc < 2; ++cc) {
      int cid = tid + cc * 256;
      int m = cid >> 2, g = cid & 3;
      int h = hb + g * 8;
      float v[8];
      #pragma unroll
      for (int e = 0; e < 8; ++e) v[e] = cbv;
      #pragma unroll
      for (int ci = 0; ci < CIN; ++ci) {
        const float* xr = X[ci] + (size_t)(m0 + m) * HD + h;
        float4 a4 = *(const float4*)xr;
        float4 b4 = *(const float4*)(xr + 4);
        float xm[8] = {a4.x, a4.y, a4.z, a4.w, b4.x, b4.y, b4.z, b4.w};
        float xl = (h > 0) ? xr[-1] : 0.f;
        float xrr = (h + 8 < HD) ? xr[8] : 0.f;
        float w0 = wv[ci][0], w1 = wv[ci][1], w2 = wv[ci][2];
        #pragma unroll
        for (int e = 0; e < 8; ++e) {
          float lft = e ? xm[e - 1] : xl;
          float rgt = (e < 7) ? xm[e + 1] : xrr;
          v[e] = fmaf(lft, w0, fmaf(xm[e], w1, fmaf(rgt, w2, v[e])));
        }
      }
      u16x8 pk;
      #pragma unroll
      for (int e = 0; e < 8; ++e) pk[e] = f2bf(fmaxf(v[e], 0.f));
      int slot = g ^ ((m >> 2) & 3);
      *(u16x8*)&As[m * 32 + slot * 8] = pk;
    }
    __syncthreads();

    // ---- MFMA ----
    bf16x8 a[4];
    #pragma unroll
    for (int i = 0; i < 4; ++i) {
      int m = wm * 64 + i * 16 + lr;
      a[i] = *(const bf16x8*)&As[m * 32 + (lg ^ ((m >> 2) & 3)) * 8];
    }
    #pragma unroll
    for (int j = 0; j < 8; ++j) {
      int nl = wn * 128 + j * 16 + lr;
      bf16x8 b = *(const bf16x8*)&Bs[nl * 32 + (lg ^ ((nl >> 2) & 3)) * 8];
      #pragma unroll
      for (int i = 0; i < 4; ++i)
        acc[i][j] = __builtin_amdgcn_mfma_f32_16x16x32_bf16(a[i], b, acc[i][j], 0, 0, 0);
    }
  }

  // ---- epilogue: write f32 partial ----
  #pragma unroll
  for (int i = 0; i < 4; ++i) {
    int mrow = m0 + wm * 64 + i * 16 + lg * 4;
    #pragma unroll
    for (int j = 0; j < 8; ++j) {
      int ncol = n0 + wn * 128 + j * 16 + lr;
      #pragma unroll
      for (int q = 0; q < 4; ++q)
        part[(size_t)(mrow + q) * HD + ncol] = acc[i][j][q];
    }
  }
}

// ---------------------------------------------------------------------------
// reduce 4 split-K partials + bias + relu -> f32 out AND bf16 out
// ---------------------------------------------------------------------------
__global__ void reduce4_kernel(const float* __restrict__ pE, const float* __restrict__ pR,
                               const float* __restrict__ bE, const float* __restrict__ bR,
                               float* __restrict__ oE, float* __restrict__ oR,
                               unsigned short* __restrict__ obE, unsigned short* __restrict__ obR) {
  int p = blockIdx.y;
  const float* part = p ? pR : pE;
  const float* bias = p ? bR : bE;
  float* o = p ? oR : oE;
  unsigned short* ob = p ? obR : obE;
  int i = blockIdx.x * 256 + threadIdx.x;    // per float4; total NB*HD/4
  int col = (i << 2) & 511;
  float4 s = *(const float4*)&part[(size_t)i * 4];
  #pragma unroll
  for (int ks = 1; ks < 4; ++ks) {
    float4 t = *(const float4*)&part[(size_t)ks * (NB * HD) + i * 4];
    s.x += t.x; s.y += t.y; s.z += t.z; s.w += t.w;
  }
  float4 b4 = *(const float4*)&bias[col];
  s.x = fmaxf(s.x + b4.x, 0.f); s.y = fmaxf(s.y + b4.y, 0.f);
  s.z = fmaxf(s.z + b4.z, 0.f); s.w = fmaxf(s.w + b4.w, 0.f);
  *(float4*)&o[(size_t)i * 4] = s;
  u16x4 pk = {f2bf(s.x), f2bf(s.y), f2bf(s.z), f2bf(s.w)};
  *(u16x4*)&ob[(size_t)i * 4] = pk;
}

// ---------------------------------------------------------------------------
// bf16 NT GEMM: C(MxN, f32) = A(MxK) @ B(NxK)^T, both bf16 row-major.
// BM=BN=128, BK=64, 4 waves (2x2), wave tile 64x64. N-tail guarded.
// ---------------------------------------------------------------------------
__global__ __launch_bounds__(256, 3)
void gemm_nt_bf16(const unsigned short* __restrict__ A, const unsigned short* __restrict__ B,
                  float* __restrict__ C, int M, int N, int K) {
  __shared__ unsigned short As[128 * 64];   // 16KB: row*64 + (chunk ^ (row&7))*8
  __shared__ unsigned short Bs[128 * 64];
  const int tid = threadIdx.x;
  const int lane = tid & 63;
  const int w = tid >> 6;
  const int wm = w >> 1, wn = w & 1;
  const int m0 = blockIdx.x * 128, n0 = blockIdx.y * 128;
  const int lr = lane & 15, lg = lane >> 4;

  f32x4 acc[4][4];
  #pragma unroll
  for (int i = 0; i < 4; ++i)
    #pragma unroll
    for (int j = 0; j < 4; ++j) acc[i][j] = (f32x4){0.f, 0.f, 0.f, 0.f};

  for (int k0 = 0; k0 < K; k0 += 64) {
    __syncthreads();
    {
      int row = tid >> 1, half = tid & 1;
      const unsigned short* asrc = A + (size_t)(m0 + row) * K + k0 + half * 32;
      #pragma unroll
      for (int q = 0; q < 4; ++q) {
        int chunk = half * 4 + q;
        *(u16x8*)&As[row * 64 + (chunk ^ (row & 7)) * 8] = *(const u16x8*)&asrc[q * 8];
      }
      int nrow = n0 + row;
      const unsigned short* bsrc = B + (size_t)nrow * K + k0 + half * 32;
      u16x8 z = {0, 0, 0, 0, 0, 0, 0, 0};
      #pragma unroll
      for (int q = 0; q < 4; ++q) {
        int chunk = half * 4 + q;
        u16x8 v = (nrow < N) ? *(const u16x8*)&bsrc[q * 8] : z;
        *(u16x8*)&Bs[row * 64 + (chunk ^ (row & 7)) * 8] = v;
      }
    }
    __syncthreads();
    #pragma unroll
    for (int u = 0; u < 2; ++u) {
      bf16x8 a[4], b[4];
      #pragma unroll
      for (int i = 0; i < 4; ++i) {
        int r = wm * 64 + i * 16 + lr;
        a[i] = *(const bf16x8*)&As[r * 64 + (((u * 4 + lg) ^ (r & 7))) * 8];
        int n = wn * 64 + i * 16 + lr;
        b[i] = *(const bf16x8*)&Bs[n * 64 + (((u * 4 + lg) ^ (n & 7))) * 8];
      }
      #pragma unroll
      for (int i = 0; i < 4; ++i)
        #pragma unroll
        for (int j = 0; j < 4; ++j)
          acc[i][j] = __builtin_amdgcn_mfma_f32_16x16x32_bf16(a[i], b[j], acc[i][j], 0, 0, 0);
    }
  }

  #pragma unroll
  for (int i = 0; i < 4; ++i) {
    int m = m0 + wm * 64 + i * 16 + lg * 4;
    #pragma unroll
    for (int j = 0; j < 4; ++j) {
      int n = n0 + wn * 64 + j * 16 + lr;
      if (n < N) {
        #pragma unroll
        for (int q = 0; q < 4; ++q)
          C[(size_t)(m + q) * N + n] = acc[i][j][q];
      }
    }
  }
}

// ---------------------------------------------------------------------------
extern "C" void kernel_launch(void* const* d_in, const int* in_sizes, int n_in,
                              void* d_out, int out_size, void* d_ws, size_t ws_size,
                              hipStream_t stream) {
  const float* ent_embeds = (const float*)d_in[0];
  const float* rel_embeds = (const float*)d_in[1];
  const float* W_msg  = (const float*)d_in[2];
  const float* W_self = (const float*)d_in[3];
  const float* gru_Wih = (const float*)d_in[4];
  const float* gru_Whh = (const float*)d_in[5];
  const float* gru_bih = (const float*)d_in[6];
  const float* gru_bhh = (const float*)d_in[7];
  const float* gate_W = (const float*)d_in[8];
  const float* gate_b = (const float*)d_in[9];
  const float* e_conv1 = (const float*)d_in[10]; const float* e_cb1 = (const float*)d_in[11];
  const float* e_fc1   = (const float*)d_in[12]; const float* e_fb1 = (const float*)d_in[13];
  const float* e_conv2 = (const float*)d_in[14]; const float* e_cb2 = (const float*)d_in[15];
  const float* e_fc2   = (const float*)d_in[16]; const float* e_fb2 = (const float*)d_in[17];
  const float* r_conv1 = (const float*)d_in[18]; const float* r_cb1 = (const float*)d_in[19];
  const float* r_fc1   = (const float*)d_in[20]; const float* r_fb1 = (const float*)d_in[21];
  const float* r_conv2 = (const float*)d_in[22]; const float* r_cb2 = (const float*)d_in[23];
  const float* r_fc2   = (const float*)d_in[24]; const float* r_fb2 = (const float*)d_in[25];
  const int* src  = (const int*)d_in[26];
  const int* dst  = (const int*)d_in[27];
  const int* erel = (const int*)d_in[28];
  const int* subj = (const int*)d_in[29];
  const int* rel  = (const int*)d_in[30];
  const int* obj  = (const int*)d_in[31];
  float* out = (float*)d_out;

  // -------- workspace layout --------
  float* w = (float*)d_ws;
  float* ent   = w; w += (size_t)N_ENT * HD;
  float* relh  = w; w += (size_t)N_REL * HD;
  float* aggR  = w; w += (size_t)N_REL * HD;
  float* cntR  = w; w += N_REL;
  float* precomp = w; w += (size_t)N_REL * 1536;
  float* gi    = w; w += (size_t)N_REL * 1536;
  float* gh    = w; w += (size_t)N_REL * 1536;
  float* aggE  = w; w += (size_t)N_ENT * HD;     // } this region (aggE..h1b, ~41M f32)
  float* cntE  = w; w += N_ENT;                  // } is reused after the recurrence
  float* tmp   = w; w += (size_t)N_ENT * HD;     // } as packed-fw storage (33.6M f32)
  float* h0b   = w; w += (size_t)N_ENT * HD;
  float* h1b   = w; w += (size_t)N_ENT * HD;
  float* se    = w; w += (size_t)NB * HD;
  float* re_   = w; w += (size_t)NB * HD;
  float* oe    = w; w += (size_t)NB * HD;
  float* o1    = w; w += (size_t)NB * HD;
  float* q1    = w; w += (size_t)NB * HD;
  float* o2    = w; w += (size_t)NB * HD;        // (unused f32 slots kept for layout)
  float* q2    = w; w += (size_t)NB * HD;
  unsigned short* ent_bf = (unsigned short*)w; w += (size_t)N_ENT * HD / 2;
  unsigned short* relh_bf = (unsigned short*)w; w += (size_t)N_REL * HD / 2;
  unsigned short* o1b = (unsigned short*)w; w += (size_t)NB * HD / 2;
  unsigned short* q1b = (unsigned short*)w; w += (size_t)NB * HD / 2;
  unsigned short* o2b = (unsigned short*)w; w += (size_t)NB * HD / 2;
  unsigned short* q2b = (unsigned short*)w; w += (size_t)NB * HD / 2;
  float* pE = w; w += (size_t)4 * NB * HD;       // split-K partials
  float* pR = w; w += (size_t)4 * NB * HD;
  // packed fw aliases the recurrence temporaries (safe: used only after loop)
  unsigned short* fwp0 = (unsigned short*)aggE;
  unsigned short* fwp1 = fwp0 + (size_t)16777216;
  unsigned short* fwp2 = fwp1 + (size_t)16777216;
  unsigned short* fwp3 = fwp2 + (size_t)16777216;

  const dim3 g_gru(2, 12);     // 256 x 1536
  const dim3 g_ent(157, 4);    // 20000 x 512

  // -------- init --------
  rownorm_kernel<<<N_ENT / 4, 256, 0, stream>>>(ent_embeds, ent, N_ENT);
  hipMemcpyAsync(relh, rel_embeds, (size_t)N_REL * HD * 4, hipMemcpyDeviceToDevice, stream);
  gemm128_kernel<0, 0, 1, 0><<<g_gru, 256, 0, stream>>>(
      rel_embeds, gru_Wih + (size_t)512 * 1536, gru_bih, nullptr, precomp, N_REL, 1536, HD);

  // -------- timestep loop (fp32, unchanged) --------
  for (int t = 0; t < NT; ++t) {
    const int* st = src + t * NE;
    const int* dt = dst + t * NE;
    const int* rt = erel + t * NE;

    hipMemsetAsync(aggR, 0, ((size_t)N_REL * HD + N_REL) * 4, stream);
    agg_rel_kernel<<<NE / 4, 256, 0, stream>>>(ent, st, rt, aggR, cntR);
    meandiv_kernel<<<(N_REL * HD / 4) / 256, 256, 0, stream>>>(aggR, cntR, N_REL);
    gemm128_kernel<0, 1, 0, 0><<<g_gru, 256, 0, stream>>>(
        aggR, gru_Wih, nullptr, precomp, gi, N_REL, 1536, HD);
    gemm128_kernel<0, 0, 1, 0><<<g_gru, 256, 0, stream>>>(
        relh, gru_Whh, gru_bhh, nullptr, gh, N_REL, 1536, HD);
    gru_kernel<<<(N_REL * HD) / 256, 256, 0, stream>>>(gi, gh, relh);

    const float* hcur = ent;
    float* bufs[2] = {h0b, h1b};
    for (int l = 0; l < 2; ++l) {
      hipMemsetAsync(aggE, 0, ((size_t)N_ENT * HD + N_ENT) * 4, stream);
      agg_ent_kernel<<<NE / 4, 256, 0, stream>>>(hcur, relh, st, dt, rt, aggE, cntE);
      meandiv_kernel<<<(N_ENT * HD / 4 + 255) / 256, 256, 0, stream>>>(aggE, cntE, N_ENT);
      gemm128_kernel<0, 0, 0, 0><<<g_ent, 256, 0, stream>>>(
          aggE, W_msg + (size_t)l * HD * HD, nullptr, nullptr, tmp, N_ENT, HD, HD);
      gemm128_kernel<0, 1, 0, 1><<<g_ent, 256, 0, stream>>>(
          hcur, W_self + (size_t)l * HD * HD, nullptr, tmp, bufs[l], N_ENT, HD, HD);
      hcur = bufs[l];
    }
    rownorm_kernel<<<N_ENT / 4, 256, 0, stream>>>(h1b, h1b, N_ENT);
    gemm128_kernel<0, 0, 1, 3><<<g_ent, 256, 0, stream>>>(
        h1b, gate_W, gate_b, h1b, ent, N_ENT, HD, HD);
  }

  // -------- decoder prep --------
  pack_fw_kernel<<<dim3(1024, 4), 256, 0, stream>>>(e_fc1, r_fc1, e_fc2, r_fc2,
                                                    fwp0, fwp1, fwp2, fwp3);
  f2b_kernel<<<(N_ENT * HD / 8) / 256, 256, 0, stream>>>(ent, ent_bf, N_ENT * HD);
  f2b_kernel<<<(N_REL * HD / 8) / 256, 256, 0, stream>>>(relh, relh_bf, N_REL * HD);
  gather_kernel<<<(NB * HD / 4) / 256, 256, 0, stream>>>(ent, subj, se, NB);
  gather_kernel<<<(NB * HD / 4) / 256, 256, 0, stream>>>(relh, rel, re_, NB);
  gather_kernel<<<(NB * HD / 4) / 256, 256, 0, stream>>>(ent, obj, oe, NB);

  // -------- decoder stage 1 --------
  convfc_mfma<2><<<dim3(32, 2, 8), 256, 0, stream>>>(
      se, re_, nullptr, e_conv1, e_cb1, fwp0,
      se, oe, nullptr, r_conv1, r_cb1, fwp1, pE, pR);
  reduce4_kernel<<<dim3(NB * HD / 4 / 256, 2), 256, 0, stream>>>(
      pE, pR, e_fb1, r_fb1, o1, q1, o1b, q1b);

  // -------- decoder stage 2 --------
  convfc_mfma<3><<<dim3(32, 2, 8), 256, 0, stream>>>(
      o1, se, re_, e_conv2, e_cb2, fwp2,
      q1, se, oe, r_conv2, r_cb2, fwp3, pE, pR);
  reduce4_kernel<<<dim3(NB * HD / 4 / 256, 2), 256, 0, stream>>>(
      pE, pR, e_fb2, r_fb2, o2, q2, o2b, q2b);

  // -------- logits (bf16 MFMA) --------
  size_t off0 = 0;
  size_t off1 = (size_t)NB * N_ENT;
  size_t off2 = off1 + (size_t)NB * N_REL;
  size_t off3 = off2 + (size_t)NB * N_ENT;
  gemm_nt_bf16<<<dim3(32, 157), 256, 0, stream>>>(o1b, ent_bf, out + off0, NB, N_ENT, HD);
  gemm_nt_bf16<<<dim3(32, 2), 256, 0, stream>>>(q1b, relh_bf, out + off1, NB, N_REL, HD);
  gemm_nt_bf16<<<dim3(32, 157), 256, 0, stream>>>(o2b, ent_bf, out + off2, NB, N_ENT, HD);
  gemm_nt_bf16<<<dim3(32, 2), 256, 0, stream>>>(q2b, relh_bf, out + off3, NB, N_REL, HD);
}

// Round 3
// 7280.649 us; speedup vs baseline: 6.5929x; 1.7767x over previous
//
#include <hip/hip_runtime.h>
#include <math.h>

// ---------------------------------------------------------------------------
// Refine (RE-GCN style): bf16-MFMA recurrence + decoder; f32 state.
// N_ENT=20000 N_REL=256 H=512 C=64 K=3 L=2 T=8 E=30000 B=4096
// ---------------------------------------------------------------------------

#define N_ENT 20000
#define N_REL 256
#define HD    512
#define NE    30000
#define NB    4096
#define NT    8

typedef __attribute__((ext_vector_type(8))) short          bf16x8;
typedef __attribute__((ext_vector_type(4))) float          f32x4;
typedef __attribute__((ext_vector_type(8))) unsigned short u16x8;
typedef __attribute__((ext_vector_type(4))) unsigned short u16x4;

static __device__ __forceinline__ float sigmoidf_(float x) {
  return 1.0f / (1.0f + expf(-x));
}
static __device__ __forceinline__ unsigned short f2bf(float f) {  // RNE
  unsigned u = __float_as_uint(f);
  return (unsigned short)((u + 0x7FFFu + ((u >> 16) & 1u)) >> 16);
}

// ---------------- row L2 normalize: out = x / (||x|| + 1e-8) ---------------
__global__ void rownorm_kernel(const float* __restrict__ in, float* __restrict__ out, int rows) {
  int wid = (blockIdx.x * blockDim.x + threadIdx.x) >> 6;
  int lane = threadIdx.x & 63;
  if (wid >= rows) return;
  const float4* ip = (const float4*)(in + (size_t)wid * HD);
  float4 v0 = ip[lane];
  float4 v1 = ip[lane + 64];
  float s = v0.x * v0.x + v0.y * v0.y + v0.z * v0.z + v0.w * v0.w
          + v1.x * v1.x + v1.y * v1.y + v1.z * v1.z + v1.w * v1.w;
  #pragma unroll
  for (int m = 1; m < 64; m <<= 1) s += __shfl_xor(s, m);
  float inv = 1.0f / (sqrtf(s) + 1e-8f);
  float4* op = (float4*)(out + (size_t)wid * HD);
  v0.x *= inv; v0.y *= inv; v0.z *= inv; v0.w *= inv;
  v1.x *= inv; v1.y *= inv; v1.z *= inv; v1.w *= inv;
  op[lane] = v0; op[lane + 64] = v1;
}

// ---------------- relation aggregation: agg[r] += ent[s], cnt[r]++ ----------
__global__ void agg_rel_kernel(const float* __restrict__ ent, const int* __restrict__ src,
                               const int* __restrict__ erel,
                               float* __restrict__ agg, float* __restrict__ cnt) {
  int wid = (blockIdx.x * blockDim.x + threadIdx.x) >> 6;
  int lane = threadIdx.x & 63;
  if (wid >= NE) return;
  int s = src[wid], r = erel[wid];
  const float* row = ent + (size_t)s * HD;
  float* arow = agg + (size_t)r * HD;
  #pragma unroll
  for (int j = 0; j < 8; ++j) atomicAdd(&arow[lane + 64 * j], row[lane + 64 * j]);
  if (lane == 0) atomicAdd(&cnt[r], 1.0f);
}

// ------------- entity aggregation: agg[d] += h[s] + relh[r], cnt[d]++ -------
__global__ void agg_ent_kernel(const float* __restrict__ h, const float* __restrict__ relh,
                               const int* __restrict__ src, const int* __restrict__ dst,
                               const int* __restrict__ erel,
                               float* __restrict__ agg, float* __restrict__ cnt) {
  int wid = (blockIdx.x * blockDim.x + threadIdx.x) >> 6;
  int lane = threadIdx.x & 63;
  if (wid >= NE) return;
  int s = src[wid], d = dst[wid], r = erel[wid];
  const float* hr = h + (size_t)s * HD;
  const float* rr = relh + (size_t)r * HD;
  float* arow = agg + (size_t)d * HD;
  #pragma unroll
  for (int j = 0; j < 8; ++j) {
    int i = lane + 64 * j;
    atomicAdd(&arow[i], hr[i] + rr[i]);
  }
  if (lane == 0) atomicAdd(&cnt[d], 1.0f);
}

// ---------------- buf[row,:] /= max(cnt[row],1) -----------------------------
__global__ void meandiv_kernel(float* __restrict__ buf, const float* __restrict__ cnt, int rows) {
  int idx = blockIdx.x * blockDim.x + threadIdx.x;
  if (idx >= rows * (HD / 4)) return;
  int row = idx >> 7;
  float inv = 1.0f / fmaxf(cnt[row], 1.0f);
  float4* p = (float4*)buf + idx;
  float4 v = *p;
  v.x *= inv; v.y *= inv; v.z *= inv; v.w *= inv;
  *p = v;
}

// ---------------- GRU elementwise (biases folded in here) ------------------
__global__ void gru_kernel(const float* __restrict__ gi, const float* __restrict__ gh,
                           const float* __restrict__ bih, const float* __restrict__ bhh,
                           float* __restrict__ relh) {
  int i = blockIdx.x * blockDim.x + threadIdx.x;
  if (i >= N_REL * HD) return;
  int row = i >> 9, col = i & 511;
  const float* gir = gi + (size_t)row * 1536;
  const float* ghr = gh + (size_t)row * 1536;
  float ir = gir[col] + bih[col];
  float iz = gir[col + 512] + bih[col + 512];
  float inn = gir[col + 1024] + bih[col + 1024];
  float hr = ghr[col] + bhh[col];
  float hz = ghr[col + 512] + bhh[col + 512];
  float hn = ghr[col + 1024] + bhh[col + 1024];
  float r = sigmoidf_(ir + hr);
  float z = sigmoidf_(iz + hz);
  float n = tanhf(inn + r * hn);
  relh[i] = (1.0f - z) * n + z * relh[i];
}

// ---------------- gather rows (f32) ----------------------------------------
__global__ void gather_kernel(const float* __restrict__ table, const int* __restrict__ idx,
                              float* __restrict__ out, int rows) {
  int i = blockIdx.x * blockDim.x + threadIdx.x;
  if (i >= rows * (HD / 4)) return;
  int row = i >> 7, q = i & 127;
  ((float4*)out)[i] = ((const float4*)(table + (size_t)idx[row] * HD))[q];
}

// ---------------- flat f32 -> bf16 convert (n multiple of 8) ---------------
__global__ void f2b_kernel(const float* __restrict__ in, unsigned short* __restrict__ out, int n) {
  int i = blockIdx.x * blockDim.x + threadIdx.x;
  if (i * 8 >= n) return;
  float4 a = *(const float4*)&in[i * 8];
  float4 b = *(const float4*)&in[i * 8 + 4];
  u16x8 pk = {f2bf(a.x), f2bf(a.y), f2bf(a.z), f2bf(a.w),
              f2bf(b.x), f2bf(b.y), f2bf(b.z), f2bf(b.w)};
  *(u16x8*)&out[i * 8] = pk;
}

// ---------------------------------------------------------------------------
// pack_nn: B (KxN f32 row-major) -> bf16 LDS-image layout:
// step s (32 k): idx = (s*N + n)*32 + ((g ^ ((n>>2)&3))<<3) + j  holds
// B[s*32 + g*8 + j][n].  One thread per u16x8.
// ---------------------------------------------------------------------------
__global__ void pack_nn_kernel(const float* __restrict__ B, unsigned short* __restrict__ out,
                               int K, int N) {
  int id = blockIdx.x * 256 + threadIdx.x;
  if (id >= (K >> 3) * N) return;
  int s = id / (N * 4);
  int rem = id - s * (N * 4);
  int n = rem >> 2, g = rem & 3;
  const float* src = B + (size_t)(s * 32 + g * 8) * N + n;
  u16x8 pk;
  #pragma unroll
  for (int j = 0; j < 8; ++j) pk[j] = f2bf(src[(size_t)j * N]);
  *(u16x8*)&out[((size_t)s * N + n) * 32 + ((g ^ ((n >> 2) & 3)) << 3)] = pk;
}

// ---------------------------------------------------------------------------
// bf16 NN GEMM with f32 A (converted during staging) and pre-packed B image.
// A = [A0 (M x K0) | A1 (M x K1)] concatenated along K (K0 % 64 == 0).
// BM=BN=128, BK=64, 4 waves (2x2), wave tile 64x64.
// ACT: 0 plain store, 1 relu, 3 gate: u=sigmoid(acc+bias[n]); C=u*D+(1-u)*C.
// ---------------------------------------------------------------------------
template <int ACT>
__global__ __launch_bounds__(256, 2)
void gemm_nn_bf16(const float* __restrict__ A0, const float* __restrict__ A1,
                  int K0, int K1,
                  const unsigned short* __restrict__ Bp,
                  const float* __restrict__ bias, const float* __restrict__ D,
                  float* __restrict__ C, int M, int N) {
  __shared__ unsigned short As[128 * 64];     // 16KB: row*64 + (chunk ^ (row&7))*8
  __shared__ unsigned short Bs[2 * 128 * 32]; // 16KB: (step*128 + nl)*32 + slot*8
  const int tid = threadIdx.x;
  const int lane = tid & 63;
  const int w = tid >> 6;
  const int wm = w >> 1, wn = w & 1;
  const int m0 = blockIdx.x * 128, n0 = blockIdx.y * 128;
  const int lr = lane & 15, lg = lane >> 4;
  const int K = K0 + K1;
  const int arow = tid >> 1;
  const int akh = (tid & 1) * 32;

  f32x4 acc[4][4];
  #pragma unroll
  for (int i = 0; i < 4; ++i)
    #pragma unroll
    for (int j = 0; j < 4; ++j) acc[i][j] = (f32x4){0.f, 0.f, 0.f, 0.f};

  for (int k0 = 0; k0 < K; k0 += 64) {
    __syncthreads();
    // ---- A stage: f32 -> bf16 into swizzled LDS ----
    {
      int mrow = m0 + arow;
      int kk = k0 + akh;                       // uniform side of K0 (K0%64==0)
      const float* base; int stride, kloc;
      if (kk < K0) { base = A0; stride = K0; kloc = kk; }
      else         { base = A1; stride = K1; kloc = kk - K0; }
      u16x8 pk[4];
      if (mrow < M) {
        const float* p = base + (size_t)mrow * stride + kloc;
        #pragma unroll
        for (int q = 0; q < 4; ++q) {
          float4 x = *(const float4*)(p + q * 8);
          float4 y = *(const float4*)(p + q * 8 + 4);
          pk[q] = (u16x8){f2bf(x.x), f2bf(x.y), f2bf(x.z), f2bf(x.w),
                          f2bf(y.x), f2bf(y.y), f2bf(y.z), f2bf(y.w)};
        }
      } else {
        #pragma unroll
        for (int q = 0; q < 4; ++q) pk[q] = (u16x8){0, 0, 0, 0, 0, 0, 0, 0};
      }
      #pragma unroll
      for (int q = 0; q < 4; ++q) {
        int chunk = (akh >> 3) + q;
        *(u16x8*)&As[arow * 64 + ((chunk ^ (arow & 7)) << 3)] = pk[q];
      }
    }
    // ---- B stage: identity copy of 2 pre-swizzled 32-k steps ----
    {
      int s0 = k0 >> 5;
      #pragma unroll
      for (int sl = 0; sl < 2; ++sl) {
        const unsigned short* src = Bp + ((size_t)(s0 + sl) * N + n0) * 32;
        #pragma unroll
        for (int q = 0; q < 2; ++q) {
          int off = (q * 256 + tid) * 8;
          *(u16x8*)&Bs[sl * 4096 + off] = *(const u16x8*)&src[off];
        }
      }
    }
    __syncthreads();
    // ---- MFMA ----
    #pragma unroll
    for (int u = 0; u < 2; ++u) {
      bf16x8 a[4], b[4];
      #pragma unroll
      for (int i = 0; i < 4; ++i) {
        int r = wm * 64 + i * 16 + lr;
        a[i] = *(const bf16x8*)&As[r * 64 + (((u * 4 + lg) ^ (r & 7)) << 3)];
        int nl = wn * 64 + i * 16 + lr;
        b[i] = *(const bf16x8*)&Bs[u * 4096 + nl * 32 + ((lg ^ ((nl >> 2) & 3)) << 3)];
      }
      #pragma unroll
      for (int i = 0; i < 4; ++i)
        #pragma unroll
        for (int j = 0; j < 4; ++j)
          acc[i][j] = __builtin_amdgcn_mfma_f32_16x16x32_bf16(a[i], b[j], acc[i][j], 0, 0, 0);
    }
  }

  // ---- epilogue ----
  #pragma unroll
  for (int i = 0; i < 4; ++i) {
    int m = m0 + wm * 64 + i * 16 + lg * 4;
    #pragma unroll
    for (int j = 0; j < 4; ++j) {
      int n = n0 + wn * 64 + j * 16 + lr;
      #pragma unroll
      for (int q = 0; q < 4; ++q) {
        int mr = m + q;
        if (mr >= M) continue;
        size_t o = (size_t)mr * N + n;
        float v = acc[i][j][q];
        if (ACT == 0) {
          C[o] = v;
        } else if (ACT == 1) {
          C[o] = fmaxf(v, 0.0f);
        } else {  // gate
          float u_ = sigmoidf_(v + bias[n]);
          C[o] = u_ * D[o] + (1.0f - u_) * C[o];
        }
      }
    }
  }
}

// ---------------------------------------------------------------------------
// pack_fw: fw (32768x512 f32) -> bf16 image (same layout as pack_nn, N=512)
// ---------------------------------------------------------------------------
__global__ __launch_bounds__(256)
void pack_fw_kernel(const float* __restrict__ f0, const float* __restrict__ f1,
                    const float* __restrict__ f2, const float* __restrict__ f3,
                    unsigned short* __restrict__ o0, unsigned short* __restrict__ o1,
                    unsigned short* __restrict__ o2, unsigned short* __restrict__ o3) {
  __shared__ float L[32][512];
  const float* fw; unsigned short* op;
  switch (blockIdx.y) {
    case 0: fw = f0; op = o0; break;
    case 1: fw = f1; op = o1; break;
    case 2: fw = f2; op = o2; break;
    default: fw = f3; op = o3; break;
  }
  int s = blockIdx.x, tid = threadIdx.x;
  #pragma unroll
  for (int i = 0; i < 16; ++i) {
    int idx = tid + 256 * i;
    int r = idx >> 7, cq = (idx & 127) << 2;
    *(float4*)&L[r][cq] = *(const float4*)&fw[(size_t)(s * 32 + r) * 512 + cq];
  }
  __syncthreads();
  #pragma unroll
  for (int ii = 0; ii < 8; ++ii) {
    int slot = tid + 256 * ii;
    int n = slot >> 2, g = slot & 3;
    u16x8 pk;
    #pragma unroll
    for (int j = 0; j < 8; ++j) pk[j] = f2bf(L[g * 8 + j][n]);
    size_t off = (size_t)s * 16384 + n * 32 + ((g ^ ((n >> 2) & 3)) << 3);
    *(u16x8*)&op[off] = pk;
  }
}

// ---------------------------------------------------------------------------
// Fused conv1d('SAME',K=3)+relu -> bf16 MFMA GEMM against packed fw.
// BM=128, BN=256, BK=32. 1-D grid 512, XCD-swizzled so the 32 m-blocks
// sharing a (path,n,ks) weight slice land on ONE XCD (L2 reuse).
// ---------------------------------------------------------------------------
template <int CIN>
__global__ __launch_bounds__(256, 2)
void convfc_mfma(const float* __restrict__ X0e, const float* __restrict__ X1e,
                 const float* __restrict__ X2e, const float* __restrict__ cwE,
                 const float* __restrict__ cbE, const unsigned short* __restrict__ fwpE,
                 const float* __restrict__ X0r, const float* __restrict__ X1r,
                 const float* __restrict__ X2r, const float* __restrict__ cwR,
                 const float* __restrict__ cbR, const unsigned short* __restrict__ fwpR,
                 float* __restrict__ partE, float* __restrict__ partR) {
  __shared__ unsigned short As[128 * 32];   // 8KB
  __shared__ unsigned short Bs[256 * 32];   // 16KB

  // XCD swizzle: p%8 = XCD; XCD x owns slice-groups {2x, 2x+1}.
  const int p = blockIdx.x;
  const int xcd = p & 7, q = p >> 3;        // q in 0..63
  const int gid = xcd * 2 + (q >> 5);       // 0..15 slice group
  const int m0 = (q & 31) * 128;
  const int path = gid >> 3;
  const int n0 = ((gid >> 2) & 1) * 256;
  const int ks = gid & 3;

  const int tid = threadIdx.x;
  const int lane = tid & 63;
  const int w = tid >> 6;
  const int wm = w >> 1, wn = w & 1;

  const float* X[CIN];
  const float* cw; const float* cb; const unsigned short* fwp; float* part;
  if (path == 0) {
    X[0] = X0e; X[1] = X1e; if constexpr (CIN == 3) X[2] = X2e;
    cw = cwE; cb = cbE; fwp = fwpE; part = partE;
  } else {
    X[0] = X0r; X[1] = X1r; if constexpr (CIN == 3) X[2] = X2r;
    cw = cwR; cb = cbR; fwp = fwpR; part = partR;
  }
  part += (size_t)ks * (NB * HD);

  f32x4 acc[4][8];
  #pragma unroll
  for (int i = 0; i < 4; ++i)
    #pragma unroll
    for (int j = 0; j < 8; ++j) acc[i][j] = (f32x4){0.f, 0.f, 0.f, 0.f};

  float wv[CIN][3];
  float cbv = 0.f;
  const int lr = lane & 15, lg = lane >> 4;

  for (int sl = 0; sl < 256; ++sl) {
    int c = ks * 16 + (sl >> 4);
    int hb = (sl & 15) * 32;
    if ((sl & 15) == 0) {
      #pragma unroll
      for (int ci = 0; ci < CIN; ++ci)
        #pragma unroll
        for (int t = 0; t < 3; ++t) wv[ci][t] = cw[(c * CIN + ci) * 3 + t];
      cbv = cb[c];
    }
    __syncthreads();

    // ---- stage B: identity copy of pre-swizzled 16KB slice ----
    {
      const unsigned short* src = fwp + (size_t)(c * 16 + (sl & 15)) * 16384 + n0 * 32;
      #pragma unroll
      for (int q2 = 0; q2 < 4; ++q2) {
        int off = q2 * 2048 + tid * 8;
        *(u16x8*)&Bs[off] = *(const u16x8*)&src[off];
      }
    }
    // ---- conv A on the fly ----
    #pragma unroll
    for (int cc = 0; cc < 2; ++cc) {
      int cid = tid + cc * 256;
      int m = cid >> 2, g = cid & 3;
      int h = hb + g * 8;
      float v[8];
      #pragma unroll
      for (int e = 0; e < 8; ++e) v[e] = cbv;
      #pragma unroll
      for (int ci = 0; ci < CIN; ++ci) {
        const float* xr = X[ci] + (size_t)(m0 + m) * HD + h;
        float4 a4 = *(const float4*)xr;
        float4 b4 = *(const float4*)(xr + 4);
        float xm[8] = {a4.x, a4.y, a4.z, a4.w, b4.x, b4.y, b4.z, b4.w};
        float xl = (h > 0) ? xr[-1] : 0.f;
        float xrr = (h + 8 < HD) ? xr[8] : 0.f;
        float w0 = wv[ci][0], w1 = wv[ci][1], w2 = wv[ci][2];
        #pragma unroll
        for (int e = 0; e < 8; ++e) {
          float lft = e ? xm[e - 1] : xl;
          float rgt = (e < 7) ? xm[e + 1] : xrr;
          v[e] = fmaf(lft, w0, fmaf(xm[e], w1, fmaf(rgt, w2, v[e])));
        }
      }
      u16x8 pk;
      #pragma unroll
      for (int e = 0; e < 8; ++e) pk[e] = f2bf(fmaxf(v[e], 0.f));
      int slot = g ^ ((m >> 2) & 3);
      *(u16x8*)&As[m * 32 + slot * 8] = pk;
    }
    __syncthreads();

    // ---- MFMA ----
    bf16x8 a[4];
    #pragma unroll
    for (int i = 0; i < 4; ++i) {
      int m = wm * 64 + i * 16 + lr;
      a[i] = *(const bf16x8*)&As[m * 32 + (lg ^ ((m >> 2) & 3)) * 8];
    }
    #pragma unroll
    for (int j = 0; j < 8; ++j) {
      int nl = wn * 128 + j * 16 + lr;
      bf16x8 b = *(const bf16x8*)&Bs[nl * 32 + (lg ^ ((nl >> 2) & 3)) * 8];
      #pragma unroll
      for (int i = 0; i < 4; ++i)
        acc[i][j] = __builtin_amdgcn_mfma_f32_16x16x32_bf16(a[i], b, acc[i][j], 0, 0, 0);
    }
  }

  // ---- epilogue: write f32 partial ----
  #pragma unroll
  for (int i = 0; i < 4; ++i) {
    int mrow = m0 + wm * 64 + i * 16 + lg * 4;
    #pragma unroll
    for (int j = 0; j < 8; ++j) {
      int ncol = n0 + wn * 128 + j * 16 + lr;
      #pragma unroll
      for (int q2 = 0; q2 < 4; ++q2)
        part[(size_t)(mrow + q2) * HD + ncol] = acc[i][j][q2];
    }
  }
}

// ---------------------------------------------------------------------------
// reduce 4 split-K partials + bias + relu -> f32 out AND bf16 out
// ---------------------------------------------------------------------------
__global__ void reduce4_kernel(const float* __restrict__ pE, const float* __restrict__ pR,
                               const float* __restrict__ bE, const float* __restrict__ bR,
                               float* __restrict__ oE, float* __restrict__ oR,
                               unsigned short* __restrict__ obE, unsigned short* __restrict__ obR) {
  int p = blockIdx.y;
  const float* part = p ? pR : pE;
  const float* bias = p ? bR : bE;
  float* o = p ? oR : oE;
  unsigned short* ob = p ? obR : obE;
  int i = blockIdx.x * 256 + threadIdx.x;
  int col = (i << 2) & 511;
  float4 s = *(const float4*)&part[(size_t)i * 4];
  #pragma unroll
  for (int ks = 1; ks < 4; ++ks) {
    float4 t = *(const float4*)&part[(size_t)ks * (NB * HD) + i * 4];
    s.x += t.x; s.y += t.y; s.z += t.z; s.w += t.w;
  }
  float4 b4 = *(const float4*)&bias[col];
  s.x = fmaxf(s.x + b4.x, 0.f); s.y = fmaxf(s.y + b4.y, 0.f);
  s.z = fmaxf(s.z + b4.z, 0.f); s.w = fmaxf(s.w + b4.w, 0.f);
  *(float4*)&o[(size_t)i * 4] = s;
  u16x4 pk = {f2bf(s.x), f2bf(s.y), f2bf(s.z), f2bf(s.w)};
  *(u16x4*)&ob[(size_t)i * 4] = pk;
}

// ---------------------------------------------------------------------------
// bf16 NT GEMM: C(MxN, f32) = A(MxK) @ B(NxK)^T, both bf16 row-major.
// ---------------------------------------------------------------------------
__global__ __launch_bounds__(256, 3)
void gemm_nt_bf16(const unsigned short* __restrict__ A, const unsigned short* __restrict__ B,
                  float* __restrict__ C, int M, int N, int K) {
  __shared__ unsigned short As[128 * 64];
  __shared__ unsigned short Bs[128 * 64];
  const int tid = threadIdx.x;
  const int lane = tid & 63;
  const int w = tid >> 6;
  const int wm = w >> 1, wn = w & 1;
  const int m0 = blockIdx.x * 128, n0 = blockIdx.y * 128;
  const int lr = lane & 15, lg = lane >> 4;

  f32x4 acc[4][4];
  #pragma unroll
  for (int i = 0; i < 4; ++i)
    #pragma unroll
    for (int j = 0; j < 4; ++j) acc[i][j] = (f32x4){0.f, 0.f, 0.f, 0.f};

  for (int k0 = 0; k0 < K; k0 += 64) {
    __syncthreads();
    {
      int row = tid >> 1, half = tid & 1;
      const unsigned short* asrc = A + (size_t)(m0 + row) * K + k0 + half * 32;
      #pragma unroll
      for (int q = 0; q < 4; ++q) {
        int chunk = half * 4 + q;
        *(u16x8*)&As[row * 64 + (chunk ^ (row & 7)) * 8] = *(const u16x8*)&asrc[q * 8];
      }
      int nrow = n0 + row;
      const unsigned short* bsrc = B + (size_t)nrow * K + k0 + half * 32;
      u16x8 z = {0, 0, 0, 0, 0, 0, 0, 0};
      #pragma unroll
      for (int q = 0; q < 4; ++q) {
        int chunk = half * 4 + q;
        u16x8 v = (nrow < N) ? *(const u16x8*)&bsrc[q * 8] : z;
        *(u16x8*)&Bs[row * 64 + (chunk ^ (row & 7)) * 8] = v;
      }
    }
    __syncthreads();
    #pragma unroll
    for (int u = 0; u < 2; ++u) {
      bf16x8 a[4], b[4];
      #pragma unroll
      for (int i = 0; i < 4; ++i) {
        int r = wm * 64 + i * 16 + lr;
        a[i] = *(const bf16x8*)&As[r * 64 + (((u * 4 + lg) ^ (r & 7))) * 8];
        int n = wn * 64 + i * 16 + lr;
        b[i] = *(const bf16x8*)&Bs[n * 64 + (((u * 4 + lg) ^ (n & 7))) * 8];
      }
      #pragma unroll
      for (int i = 0; i < 4; ++i)
        #pragma unroll
        for (int j = 0; j < 4; ++j)
          acc[i][j] = __builtin_amdgcn_mfma_f32_16x16x32_bf16(a[i], b[j], acc[i][j], 0, 0, 0);
    }
  }

  #pragma unroll
  for (int i = 0; i < 4; ++i) {
    int m = m0 + wm * 64 + i * 16 + lg * 4;
    #pragma unroll
    for (int j = 0; j < 4; ++j) {
      int n = n0 + wn * 64 + j * 16 + lr;
      if (n < N) {
        #pragma unroll
        for (int q = 0; q < 4; ++q)
          C[(size_t)(m + q) * N + n] = acc[i][j][q];
      }
    }
  }
}

// ---------------------------------------------------------------------------
extern "C" void kernel_launch(void* const* d_in, const int* in_sizes, int n_in,
                              void* d_out, int out_size, void* d_ws, size_t ws_size,
                              hipStream_t stream) {
  const float* ent_embeds = (const float*)d_in[0];
  const float* rel_embeds = (const float*)d_in[1];
  const float* W_msg  = (const float*)d_in[2];
  const float* W_self = (const float*)d_in[3];
  const float* gru_Wih = (const float*)d_in[4];
  const float* gru_Whh = (const float*)d_in[5];
  const float* gru_bih = (const float*)d_in[6];
  const float* gru_bhh = (const float*)d_in[7];
  const float* gate_W = (const float*)d_in[8];
  const float* gate_b = (const float*)d_in[9];
  const float* e_conv1 = (const float*)d_in[10]; const float* e_cb1 = (const float*)d_in[11];
  const float* e_fc1   = (const float*)d_in[12]; const float* e_fb1 = (const float*)d_in[13];
  const float* e_conv2 = (const float*)d_in[14]; const float* e_cb2 = (const float*)d_in[15];
  const float* e_fc2   = (const float*)d_in[16]; const float* e_fb2 = (const float*)d_in[17];
  const float* r_conv1 = (const float*)d_in[18]; const float* r_cb1 = (const float*)d_in[19];
  const float* r_fc1   = (const float*)d_in[20]; const float* r_fb1 = (const float*)d_in[21];
  const float* r_conv2 = (const float*)d_in[22]; const float* r_cb2 = (const float*)d_in[23];
  const float* r_fc2   = (const float*)d_in[24]; const float* r_fb2 = (const float*)d_in[25];
  const int* src  = (const int*)d_in[26];
  const int* dst  = (const int*)d_in[27];
  const int* erel = (const int*)d_in[28];
  const int* subj = (const int*)d_in[29];
  const int* rel  = (const int*)d_in[30];
  const int* obj  = (const int*)d_in[31];
  float* out = (float*)d_out;

  // -------- workspace layout --------
  float* w = (float*)d_ws;
  float* ent   = w; w += (size_t)N_ENT * HD;
  float* relh  = w; w += (size_t)N_REL * HD;
  float* aggR  = w; w += (size_t)N_REL * HD;
  float* cntR  = w; w += N_REL;
  float* gi    = w; w += (size_t)N_REL * 1536;
  float* gh    = w; w += (size_t)N_REL * 1536;
  float* aggE  = w; w += (size_t)N_ENT * HD;     // } aggE..h1b reused post-loop as
  float* cntE  = w; w += N_ENT;                  // } packed-fw storage (33.6M f32
  float* tmp   = w; w += (size_t)N_ENT * HD;     // } needed; region has 41M)
  float* h0b   = w; w += (size_t)N_ENT * HD;
  float* h1b   = w; w += (size_t)N_ENT * HD;
  float* se    = w; w += (size_t)NB * HD;
  float* re_   = w; w += (size_t)NB * HD;
  float* oe    = w; w += (size_t)NB * HD;
  float* o1    = w; w += (size_t)NB * HD;
  float* q1    = w; w += (size_t)NB * HD;
  unsigned short* ent_bf = (unsigned short*)w; w += (size_t)N_ENT * HD / 2;
  unsigned short* relh_bf = (unsigned short*)w; w += (size_t)N_REL * HD / 2;
  unsigned short* o1b = (unsigned short*)w; w += (size_t)NB * HD / 2;
  unsigned short* q1b = (unsigned short*)w; w += (size_t)NB * HD / 2;
  unsigned short* o2b = (unsigned short*)w; w += (size_t)NB * HD / 2;
  unsigned short* q2b = (unsigned short*)w; w += (size_t)NB * HD / 2;
  float* pE = w; w += (size_t)4 * NB * HD;       // split-K partials
  float* pR = w; w += (size_t)4 * NB * HD;
  // recurrence weight packs (bf16), live across the whole call
  unsigned short* wp_ih = (unsigned short*)w;    // 1024x1536
  unsigned short* wp_hh = wp_ih + (size_t)1024 * 1536;   // 512x1536
  unsigned short* wp_l0 = wp_hh + (size_t)512 * 1536;    // 1024x512
  unsigned short* wp_l1 = wp_l0 + (size_t)1024 * 512;    // 1024x512
  unsigned short* wp_g  = wp_l1 + (size_t)1024 * 512;    // 512x512
  // fw packs alias the recurrence temporaries (used only post-loop)
  unsigned short* fwp0 = (unsigned short*)aggE;
  unsigned short* fwp1 = fwp0 + (size_t)16777216;
  unsigned short* fwp2 = fwp1 + (size_t)16777216;
  unsigned short* fwp3 = fwp2 + (size_t)16777216;
  (void)tmp; (void)h0b;  // part of the alias region

  // o2/q2 f32 slots (reuse se-region? keep dedicated via pE tail not needed —
  // they are only consumed by convfc stage2 inputs) -> place after q1:
  float* o2 = o1;   // stage-2 f32 outputs can reuse o1/q1? NO: o1 is stage-2 input.
  // dedicated o2/q2: carve from pE's tail is unsafe (pE in use). Use tmp tail:
  // tmp region is free during decoder EXCEPT fw packs occupy aggE..(33.6M f32).
  // alias region = aggE(10.24M)+cntE+tmp(10.24M)+h0b(10.24M)+h1b(10.24M)=40.98M
  // fw packs use first 33.55M -> last ~7.4M of h1b region is free:
  o2 = h1b + (size_t)N_ENT * HD - (size_t)2 * NB * HD - 1024;   // 2*2.1M floats
  float* q2 = o2 + (size_t)NB * HD;

  const dim3 g_gru(2, 12);     // 256 x 1536
  const dim3 g_ent(157, 4);    // 20000 x 512

  // -------- weight packing (once, before loop) --------
  {
    int t;
    t = (1024 * 1536) / 8; pack_nn_kernel<<<(t + 255) / 256, 256, 0, stream>>>(gru_Wih, wp_ih, 1024, 1536);
    t = (512 * 1536) / 8;  pack_nn_kernel<<<(t + 255) / 256, 256, 0, stream>>>(gru_Whh, wp_hh, 512, 1536);
    t = (512 * 512) / 8;
    pack_nn_kernel<<<(t + 255) / 256, 256, 0, stream>>>(W_msg, wp_l0, 512, 512);
    pack_nn_kernel<<<(t + 255) / 256, 256, 0, stream>>>(W_self, wp_l0 + (size_t)512 * 512, 512, 512);
    pack_nn_kernel<<<(t + 255) / 256, 256, 0, stream>>>(W_msg + (size_t)512 * 512, wp_l1, 512, 512);
    pack_nn_kernel<<<(t + 255) / 256, 256, 0, stream>>>(W_self + (size_t)512 * 512, wp_l1 + (size_t)512 * 512, 512, 512);
    pack_nn_kernel<<<(t + 255) / 256, 256, 0, stream>>>(gate_W, wp_g, 512, 512);
  }

  // -------- init --------
  rownorm_kernel<<<N_ENT / 4, 256, 0, stream>>>(ent_embeds, ent, N_ENT);
  hipMemcpyAsync(relh, rel_embeds, (size_t)N_REL * HD * 4, hipMemcpyDeviceToDevice, stream);

  // -------- timestep loop --------
  for (int t = 0; t < NT; ++t) {
    const int* st = src + t * NE;
    const int* dt = dst + t * NE;
    const int* rt = erel + t * NE;

    hipMemsetAsync(aggR, 0, ((size_t)N_REL * HD + N_REL) * 4, stream);
    agg_rel_kernel<<<NE / 4, 256, 0, stream>>>(ent, st, rt, aggR, cntR);
    meandiv_kernel<<<(N_REL * HD / 4) / 256, 256, 0, stream>>>(aggR, cntR, N_REL);
    // gi = [aggR | rel_embeds] @ Wih ; gh = relh @ Whh  (biases in gru_kernel)
    gemm_nn_bf16<0><<<g_gru, 256, 0, stream>>>(aggR, rel_embeds, 512, 512, wp_ih,
                                               nullptr, nullptr, gi, N_REL, 1536);
    gemm_nn_bf16<0><<<g_gru, 256, 0, stream>>>(relh, relh, 512, 0, wp_hh,
                                               nullptr, nullptr, gh, N_REL, 1536);
    gru_kernel<<<(N_REL * HD) / 256, 256, 0, stream>>>(gi, gh, gru_bih, gru_bhh, relh);

    // entity evolution: per layer ONE fused GEMM h = relu([agg|h] @ [Wmsg;Wself])
    const float* hcur = ent;
    float* bufs[2] = {h0b, h1b};
    const unsigned short* wls[2] = {wp_l0, wp_l1};
    for (int l = 0; l < 2; ++l) {
      hipMemsetAsync(aggE, 0, ((size_t)N_ENT * HD + N_ENT) * 4, stream);
      agg_ent_kernel<<<NE / 4, 256, 0, stream>>>(hcur, relh, st, dt, rt, aggE, cntE);
      meandiv_kernel<<<(N_ENT * HD / 4 + 255) / 256, 256, 0, stream>>>(aggE, cntE, N_ENT);
      gemm_nn_bf16<1><<<g_ent, 256, 0, stream>>>(aggE, hcur, 512, 512, wls[l],
                                                 nullptr, nullptr, bufs[l], N_ENT, 512);
      hcur = bufs[l];
    }
    rownorm_kernel<<<N_ENT / 4, 256, 0, stream>>>(h1b, h1b, N_ENT);
    gemm_nn_bf16<3><<<g_ent, 256, 0, stream>>>(h1b, h1b, 512, 0, wp_g,
                                               gate_b, h1b, ent, N_ENT, 512);
  }

  // -------- decoder prep --------
  pack_fw_kernel<<<dim3(1024, 4), 256, 0, stream>>>(e_fc1, r_fc1, e_fc2, r_fc2,
                                                    fwp0, fwp1, fwp2, fwp3);
  f2b_kernel<<<(N_ENT * HD / 8) / 256, 256, 0, stream>>>(ent, ent_bf, N_ENT * HD);
  f2b_kernel<<<(N_REL * HD / 8) / 256, 256, 0, stream>>>(relh, relh_bf, N_REL * HD);
  gather_kernel<<<(NB * HD / 4) / 256, 256, 0, stream>>>(ent, subj, se, NB);
  gather_kernel<<<(NB * HD / 4) / 256, 256, 0, stream>>>(relh, rel, re_, NB);
  gather_kernel<<<(NB * HD / 4) / 256, 256, 0, stream>>>(ent, obj, oe, NB);

  // -------- decoder stage 1 --------
  convfc_mfma<2><<<dim3(512), 256, 0, stream>>>(
      se, re_, nullptr, e_conv1, e_cb1, fwp0,
      se, oe, nullptr, r_conv1, r_cb1, fwp1, pE, pR);
  reduce4_kernel<<<dim3(NB * HD / 4 / 256, 2), 256, 0, stream>>>(
      pE, pR, e_fb1, r_fb1, o1, q1, o1b, q1b);

  // -------- decoder stage 2 --------
  convfc_mfma<3><<<dim3(512), 256, 0, stream>>>(
      o1, se, re_, e_conv2, e_cb2, fwp2,
      q1, se, oe, r_conv2, r_cb2, fwp3, pE, pR);
  reduce4_kernel<<<dim3(NB * HD / 4 / 256, 2), 256, 0, stream>>>(
      pE, pR, e_fb2, r_fb2, o2, q2, o2b, q2b);

  // -------- logits (bf16 MFMA) --------
  size_t off0 = 0;
  size_t off1 = (size_t)NB * N_ENT;
  size_t off2 = off1 + (size_t)NB * N_REL;
  size_t off3 = off2 + (size_t)NB * N_ENT;
  gemm_nt_bf16<<<dim3(32, 157), 256, 0, stream>>>(o1b, ent_bf, out + off0, NB, N_ENT, HD);
  gemm_nt_bf16<<<dim3(32, 2), 256, 0, stream>>>(q1b, relh_bf, out + off1, NB, N_REL, HD);
  gemm_nt_bf16<<<dim3(32, 157), 256, 0, stream>>>(o2b, ent_bf, out + off2, NB, N_ENT, HD);
  gemm_nt_bf16<<<dim3(32, 2), 256, 0, stream>>>(q2b, relh_bf, out + off3, NB, N_REL, HD);
}